// Round 9
// baseline (304.150 us; speedup 1.0000x reference)
//
#include <hip/hip_runtime.h>
#include <math.h>

#define EMB 256

typedef _Float16 half8 __attribute__((ext_vector_type(8)));
typedef float f32x4 __attribute__((ext_vector_type(4)));

// 8 f32 -> hi/lo fp16 split: x ~= hi + lo to ~2^-22 rel.
__device__ __forceinline__ void split8(const f32x4 a, const f32x4 b,
                                       half8& hi, half8& lo) {
#pragma unroll
    for (int i = 0; i < 4; ++i) {
        hi[i]     = (_Float16)a[i];
        lo[i]     = (_Float16)(a[i] - (float)hi[i]);
        hi[4 + i] = (_Float16)b[i];
        lo[4 + i] = (_Float16)(b[i] - (float)hi[4 + i]);
    }
}

// Pre-split W (Wh,Wt: 256x256 f32) into f16 hi/lo, MFMA-fragment-ordered:
// dst[r*512 + c*64 + seg*8]      = hi of k = c*32 + seg*8 .. +8
// dst[r*512 + c*64 + 32 + seg*8] = lo of same k-run
// (c = k/32 chunk, seg = (k/8)&3). No swizzle: consumed by direct reg loads.
__global__ void presplit_w(const float* __restrict__ Wh, const float* __restrict__ Wt,
                           _Float16* __restrict__ Whs, _Float16* __restrict__ Wts)
{
    const int g = blockIdx.x * 256 + threadIdx.x;   // 16384 granules
    const int m = g >> 5;                  // 0..511
    const int cs = g & 31;
    const int c = cs >> 2, seg = cs & 3;
    const float* src = (m < 256) ? Wh : Wt;
    _Float16* dst    = (m < 256) ? Whs : Wts;
    const int r = m & 255;

    const float* s = src + (size_t)r * EMB + c * 32 + seg * 8;
    const f32x4 v0 = *(const f32x4*)s;
    const f32x4 v1 = *(const f32x4*)(s + 4);
    half8 hi, lo;
    split8(v0, v1, hi, lo);
    _Float16* d = dst + (size_t)r * 512 + c * 64 + seg * 8;
    *(half8*)d        = hi;
    *(half8*)(d + 32) = lo;
}

// LDS-free, barrier-free GEMM. Each block -> one 128x128 tile of
// H = X*Wh^T + bh or T = X*Wt^T + bt (variant = wg&3: bit0 = n-half,
// bit1 = head/tail). 3-term split-f16 MFMA (hi*hi + hi*lo + lo*hi).
// MFMA A/B fragments are loaded DIRECTLY from global into registers:
// lane (l15,l4) reads 16B at row (..+l15), k-run l4*8 — B from the
// pre-split f16 (L2-resident, 0.5 MB), A as f32 split in-reg. No LDS,
// no __syncthreads -> no vmcnt(0) drains; the compiler software-pipelines
// next-chunk loads under the current chunk's MFMAs with counted waitcnts.
// XCD-swizzled grid keeps the 4 variants of each m-tile + neighbors on one
// XCD's L2, so X is HBM-fetched once and L2-served thereafter.
__global__ __launch_bounds__(256, 3)
void gemm_direct(const float* __restrict__ X,
                 const _Float16* __restrict__ Whs, const _Float16* __restrict__ Wts,
                 const float* __restrict__ bh, const float* __restrict__ bt,
                 float* __restrict__ Hout, float* __restrict__ Tout,
                 int M, int nwg)
{
    // bijective XCD swizzle (m204)
    const int fl = blockIdx.x;
    const int q = nwg >> 3, r = nwg & 7;
    const int xcd = fl & 7, ix = fl >> 3;
    const int wg = (xcd < r) ? xcd * (q + 1) + ix
                             : r * (q + 1) + (xcd - r) * q + ix;
    const int variant = wg & 3;
    const int m0 = (wg >> 2) << 7;
    const int n0 = (variant & 1) << 7;
    const int sel = variant >> 1;
    const _Float16* __restrict__ Ws = sel ? Wts : Whs;
    const float* __restrict__ bias  = sel ? bt : bh;
    float* __restrict__ OUT         = sel ? Tout : Hout;

    const int tid = threadIdx.x;
    const int lane = tid & 63;
    const int wv = tid >> 6;
    const int wm = (wv >> 1) << 6;     // 0 / 64
    const int wn = (wv & 1) << 6;      // 0 / 64
    const int l15 = lane & 15, l4 = lane >> 4;

    // per-fragment global pointers (k-base for chunk 0)
    const float* aP[4];
#pragma unroll
    for (int fi = 0; fi < 4; ++fi) {
        int row = m0 + wm + fi * 16 + l15;
        if (row >= M) row = M - 1;                 // loads valid; stores guarded
        aP[fi] = X + (size_t)row * EMB + l4 * 8;
    }
    const _Float16* bP[4];
#pragma unroll
    for (int j = 0; j < 4; ++j)
        bP[j] = Ws + (size_t)(n0 + wn + j * 16 + l15) * 512 + l4 * 8;

    f32x4 acc[4][4];
#pragma unroll
    for (int i = 0; i < 4; ++i)
#pragma unroll
        for (int j = 0; j < 4; ++j) acc[i][j] = (f32x4){0.f, 0.f, 0.f, 0.f};

#pragma unroll
    for (int c = 0; c < 8; ++c) {
        half8 ah[4], al[4];
#pragma unroll
        for (int fi = 0; fi < 4; ++fi) {
            const float* ap = aP[fi] + c * 32;
            const f32x4 a0 = *(const f32x4*)ap;
            const f32x4 a1 = *(const f32x4*)(ap + 4);
            split8(a0, a1, ah[fi], al[fi]);
        }
#pragma unroll
        for (int j = 0; j < 4; ++j) {
            const _Float16* bp = bP[j] + c * 64;
            const half8 bh8 = *(const half8*)bp;
            const half8 bl8 = *(const half8*)(bp + 32);
#pragma unroll
            for (int i = 0; i < 4; ++i) {
                acc[i][j] = __builtin_amdgcn_mfma_f32_16x16x32_f16(ah[i], bh8, acc[i][j], 0, 0, 0);
                acc[i][j] = __builtin_amdgcn_mfma_f32_16x16x32_f16(ah[i], bl8, acc[i][j], 0, 0, 0);
                acc[i][j] = __builtin_amdgcn_mfma_f32_16x16x32_f16(al[i], bh8, acc[i][j], 0, 0, 0);
            }
        }
    }

    // epilogue: C/D layout col = lane&15, row = (lane>>4)*4 + reg (m89)
    float bv[4];
#pragma unroll
    for (int j = 0; j < 4; ++j) bv[j] = bias[n0 + wn + j * 16 + l15];

#pragma unroll
    for (int i = 0; i < 4; ++i) {
        const int rbase = m0 + wm + i * 16 + l4 * 4;
#pragma unroll
        for (int rg = 0; rg < 4; ++rg) {
            const int gr = rbase + rg;
            if (gr < M) {
                float* dst = &OUT[(size_t)gr * EMB + n0 + wn];
#pragma unroll
                for (int j = 0; j < 4; ++j)
                    dst[j * 16 + l15] = acc[i][j][rg] + bv[j];
            }
        }
    }
}

// Four edges per wave: 12 outstanding row-gathers for memory-level parallelism.
__global__ __launch_bounds__(256)
void edge_score4(const float* __restrict__ H, const float* __restrict__ T,
                 const float* __restrict__ rel, const int* __restrict__ ei,
                 const int* __restrict__ et, float* __restrict__ out, int E)
{
    const int lane = threadIdx.x & 63;
    const int wid = threadIdx.x >> 6;
    const int base = (blockIdx.x * 4 + wid) * 4;
    if (base >= E) return;

    int e[4];
#pragma unroll
    for (int u = 0; u < 4; ++u) {
        int eu = base + u;
        e[u] = eu < E ? eu : E - 1;      // clamp: dup work, identical writes
    }

    const int lo = lane * 4;
    float4 h[4], t[4], g[4];
#pragma unroll
    for (int u = 0; u < 4; ++u) h[u] = *(const float4*)&H[(size_t)ei[e[u]] * EMB + lo];
#pragma unroll
    for (int u = 0; u < 4; ++u) t[u] = *(const float4*)&T[(size_t)ei[E + e[u]] * EMB + lo];
#pragma unroll
    for (int u = 0; u < 4; ++u) g[u] = *(const float4*)&rel[(size_t)et[e[u]] * EMB + lo];

    float p[4];
#pragma unroll
    for (int u = 0; u < 4; ++u)
        p[u] = h[u].x * g[u].x * t[u].x + h[u].y * g[u].y * t[u].y
             + h[u].z * g[u].z * t[u].z + h[u].w * g[u].w * t[u].w;

#pragma unroll
    for (int off = 32; off > 0; off >>= 1) {
#pragma unroll
        for (int u = 0; u < 4; ++u) p[u] += __shfl_xor(p[u], off, 64);
    }
    if (lane == 0) {
#pragma unroll
        for (int u = 0; u < 4; ++u)
            out[e[u]] = 1.0f / (1.0f + expf(-p[u]));
    }
}

// Last-resort fallback: one block per edge, direct fp32 matvecs.
__global__ __launch_bounds__(256)
void edge_direct(const float* __restrict__ X, const int* __restrict__ ei,
                 const int* __restrict__ et,
                 const float* __restrict__ Wh, const float* __restrict__ bh,
                 const float* __restrict__ Wt, const float* __restrict__ bt,
                 const float* __restrict__ rel, float* __restrict__ out, int E)
{
    __shared__ float xsrc[EMB], xdst[EMB];
    __shared__ float red[256];
    const int e = blockIdx.x;
    const int tid = threadIdx.x;
    const int src = ei[e], dst = ei[E + e], r = et[e];

    xsrc[tid] = X[(size_t)src * EMB + tid];
    xdst[tid] = X[(size_t)dst * EMB + tid];
    __syncthreads();

    float ah = 0.f, at = 0.f;
    const float* wh = Wh + (size_t)tid * EMB;
    const float* wt = Wt + (size_t)tid * EMB;
#pragma unroll 8
    for (int k = 0; k < EMB; k += 4) {
        float4 w4 = *(const float4*)&wh[k];
        ah += w4.x * xsrc[k] + w4.y * xsrc[k + 1] + w4.z * xsrc[k + 2] + w4.w * xsrc[k + 3];
        float4 v4 = *(const float4*)&wt[k];
        at += v4.x * xdst[k] + v4.y * xdst[k + 1] + v4.z * xdst[k + 2] + v4.w * xdst[k + 3];
    }
    red[tid] = (ah + bh[tid]) * rel[(size_t)r * EMB + tid] * (at + bt[tid]);
    __syncthreads();
    for (int s2 = 128; s2 > 0; s2 >>= 1) {
        if (tid < s2) red[tid] += red[tid + s2];
        __syncthreads();
    }
    if (tid == 0) out[e] = 1.0f / (1.0f + expf(-red[0]));
}

extern "C" void kernel_launch(void* const* d_in, const int* in_sizes, int n_in,
                              void* d_out, int out_size, void* d_ws, size_t ws_size,
                              hipStream_t stream) {
    const float* x   = (const float*)d_in[0];
    const int*   ei  = (const int*)d_in[1];
    const int*   et  = (const int*)d_in[2];
    const float* Wh  = (const float*)d_in[3];
    const float* bh  = (const float*)d_in[4];
    const float* Wt  = (const float*)d_in[5];
    const float* bt  = (const float*)d_in[6];
    const float* rel = (const float*)d_in[7];
    float* out = (float*)d_out;

    const int M = in_sizes[0] / EMB;   // 100000 nodes
    const int E = in_sizes[2];         // 250000 edges

    const size_t szHT = (size_t)2 * M * EMB * sizeof(float);        // H + T
    const size_t szWs = (size_t)2 * 256 * 512 * sizeof(_Float16);   // Whs+Wts

    if (ws_size >= szHT + szWs) {
        float* H = (float*)d_ws;
        float* T = H + (size_t)M * EMB;
        _Float16* Whs = (_Float16*)((char*)d_ws + szHT);
        _Float16* Wts = Whs + (size_t)256 * 512;

        presplit_w<<<64, 256, 0, stream>>>(Wh, Wt, Whs, Wts);
        const int mtiles = (M + 127) / 128;
        const int nwg = 4 * mtiles;
        gemm_direct<<<nwg, 256, 0, stream>>>(x, Whs, Wts, bh, bt, H, T, M, nwg);
        edge_score4<<<(E + 15) / 16, 256, 0, stream>>>(H, T, rel, ei, et, out, E);
    } else {
        edge_direct<<<E, 256, 0, stream>>>(x, ei, et, Wh, bh, Wt, bt, rel, out, E);
    }
}

// Round 10
// 208.806 us; speedup vs baseline: 1.4566x; 1.4566x over previous
//
#include <hip/hip_runtime.h>
#include <math.h>

#define EMB 256

typedef _Float16 half8 __attribute__((ext_vector_type(8)));
typedef float f32x4 __attribute__((ext_vector_type(4)));

// ---------- async global->LDS, 16B per lane ----------
__device__ __forceinline__ void gload_lds16(const void* gsrc, void* lds) {
    __builtin_amdgcn_global_load_lds(
        (const __attribute__((address_space(1))) void*)gsrc,
        (__attribute__((address_space(3))) void*)lds,
        16, 0, 0);
}

// 8 f32 -> hi/lo fp16 split: x ~= hi + lo to ~2^-22 rel.
__device__ __forceinline__ void split8(const f32x4 a, const f32x4 b,
                                       half8& hi, half8& lo) {
#pragma unroll
    for (int i = 0; i < 4; ++i) {
        hi[i]     = (_Float16)a[i];
        lo[i]     = (_Float16)(a[i] - (float)hi[i]);
        hi[4 + i] = (_Float16)b[i];
        lo[4 + i] = (_Float16)(b[i] - (float)hi[4 + i]);
    }
}

// Pre-split W (Wh,Wt: 256x256 f32) into granule-swizzled f16 hi/lo:
// dst[r*512 + c*64 + g'*8 ..+8), g = part*4+seg, g' = g ^ (r&7).
__global__ void presplit_w(const float* __restrict__ Wh, const float* __restrict__ Wt,
                           _Float16* __restrict__ Whs, _Float16* __restrict__ Wts)
{
    const int g = blockIdx.x * 256 + threadIdx.x;
    const int m = g >> 5;                  // 0..511
    const int cs = g & 31;
    const int c = cs >> 2, seg = cs & 3;
    const float* src = (m < 256) ? Wh : Wt;
    _Float16* dst    = (m < 256) ? Whs : Wts;
    const int r = m & 255;

    const float* s = src + (size_t)r * EMB + c * 32 + seg * 8;
    const f32x4 v0 = *(const f32x4*)s;
    const f32x4 v1 = *(const f32x4*)(s + 4);
    half8 hi, lo;
    split8(v0, v1, hi, lo);
    _Float16* d = dst + (size_t)r * 512 + c * 64;
    const int sw = r & 7;
    *(half8*)(d + ((seg       ^ sw) << 3)) = hi;
    *(half8*)(d + (((4 + seg) ^ sw) << 3)) = lo;
}

// Dual-output GEMM (round-7 structure): one block -> 128x128 tile of BOTH
// H = X*Wh^T + bh and T = X*Wt^T + bt. 3-term split-f16 MFMA.
// A: global->reg->split->ds_write f16 (split once per block).
// B: pre-split f16 staged by global_load_lds (zero in-loop VALU).
// Granule-XOR swizzle on all LDS layouts -> conflict-free ds_read_b128.
// __launch_bounds__(256,4): VGPR cap 128 (kernel fits in 120) so 3 blocks/CU
// co-reside (LDS-capped: 3x48KB) -> independent blocks at uncorrelated phases
// hide each other's vmcnt-drain/barrier stalls on the SIMD (m114 mechanism).
__global__ __launch_bounds__(256, 4)
void gemm_dual(const float* __restrict__ X,
               const _Float16* __restrict__ Whs, const _Float16* __restrict__ Wts,
               const float* __restrict__ bh, const float* __restrict__ bt,
               float* __restrict__ Hout, float* __restrict__ Tout,
               int M, int nwg)
{
    __shared__ __align__(16) _Float16 Ax[128 * 64];   // 16 KB (hi g0-3, lo g4-7)
    __shared__ __align__(16) _Float16 Bh[128 * 64];   // 16 KB
    __shared__ __align__(16) _Float16 Bt[128 * 64];   // 16 KB

    // bijective XCD swizzle (m204)
    const int fl = blockIdx.x;
    const int q = nwg >> 3, r = nwg & 7;
    const int xcd = fl & 7, ix = fl >> 3;
    const int wg = (xcd < r) ? xcd * (q + 1) + ix
                             : r * (q + 1) + (xcd - r) * q + ix;
    const int n0 = (wg & 1) << 7;
    const int m0 = (wg >> 1) << 7;

    const int tid = threadIdx.x;
    const int lane = tid & 63;
    const int wv = tid >> 6;
    const int wm = (wv >> 1) << 6;
    const int wn = (wv & 1) << 6;
    const int l15 = lane & 15, l4 = lane >> 4;

    // ---- A staging mapping: thread -> (row = tid>>1, 16-float half = tid&1)
    const int ar = tid >> 1;
    const int ahalf = tid & 1;
    const int gmA = m0 + ar;
    const float* aSrc = X + (size_t)(gmA < M ? gmA : M - 1) * EMB + ahalf * 16;
    char* aDst = (char*)Ax + ar * 128;
    const int ar7 = ar & 7;
    const int s0 = ahalf * 2, s1 = s0 + 1;
    const int oh0 = ((s0       ^ ar7) << 4), ol0 = (((4 + s0) ^ ar7) << 4);
    const int oh1 = ((s1       ^ ar7) << 4), ol1 = (((4 + s1) ^ ar7) << 4);

    // ---- B staging mapping: issue i: row = (tid>>3)+32i, phys granule tid&7
    const int brow = tid >> 3, bg = tid & 7;
    const char* bhSrc = (const char*)Whs + (size_t)(n0 + brow) * 1024 + bg * 16;
    const char* btSrc = (const char*)Wts + (size_t)(n0 + brow) * 1024 + bg * 16;
    char* bhDst = (char*)Bh + brow * 128 + bg * 16;
    char* btDst = (char*)Bt + brow * 128 + bg * 16;

    f32x4 accH[4][4], accT[4][4];
#pragma unroll
    for (int i = 0; i < 4; ++i)
#pragma unroll
        for (int j = 0; j < 4; ++j) {
            accH[i][j] = (f32x4){0.f, 0.f, 0.f, 0.f};
            accT[i][j] = (f32x4){0.f, 0.f, 0.f, 0.f};
        }

    // preload A chunk 0 into regs
    f32x4 xg[4];
#pragma unroll
    for (int p = 0; p < 4; ++p) xg[p] = *(const f32x4*)(aSrc + p * 4);

    for (int c = 0; c < 8; ++c) {
        if (c) __syncthreads();          // prev chunk's frag reads done
        // B gloads first: latency hides under the A-split VALU below
        const int cb = c << 7;
#pragma unroll
        for (int i = 0; i < 4; ++i) {
            gload_lds16(bhSrc + (size_t)i * 32768 + cb, bhDst + i * 4096);
            gload_lds16(btSrc + (size_t)i * 32768 + cb, btDst + i * 4096);
        }
        // A split + LDS write (once per block, not per wave)
        {
            half8 hi0, lo0, hi1, lo1;
            split8(xg[0], xg[1], hi0, lo0);
            split8(xg[2], xg[3], hi1, lo1);
            *(half8*)(aDst + oh0) = hi0;
            *(half8*)(aDst + ol0) = lo0;
            *(half8*)(aDst + oh1) = hi1;
            *(half8*)(aDst + ol1) = lo1;
        }
        __syncthreads();                 // drains vmcnt+lgkm: tiles visible

        // prefetch next A chunk (latency hidden under MFMA block)
        if (c < 7) {
            const float* an = aSrc + (c + 1) * 32;
#pragma unroll
            for (int p = 0; p < 4; ++p) xg[p] = *(const f32x4*)(an + p * 4);
        }

        half8 ahh[4], ahl[4];
#pragma unroll
        for (int fi = 0; fi < 4; ++fi) {
            const int row = wm + fi * 16 + l15;
            const char* rb = (const char*)Ax + row * 128;
            ahh[fi] = *(const half8*)(rb + (((l4    ) ^ (row & 7)) << 4));
            ahl[fi] = *(const half8*)(rb + (((l4 + 4) ^ (row & 7)) << 4));
        }
#pragma unroll
        for (int j = 0; j < 4; ++j) {
            const int n = wn + j * 16 + l15;
            const int n7 = n & 7;
            const char* hr = (const char*)Bh + n * 128;
            const char* tr = (const char*)Bt + n * 128;
            const half8 bhh = *(const half8*)(hr + (((l4    ) ^ n7) << 4));
            const half8 bhl = *(const half8*)(hr + (((l4 + 4) ^ n7) << 4));
            const half8 bth = *(const half8*)(tr + (((l4    ) ^ n7) << 4));
            const half8 btl = *(const half8*)(tr + (((l4 + 4) ^ n7) << 4));
#pragma unroll
            for (int i = 0; i < 4; ++i) {
                accH[i][j] = __builtin_amdgcn_mfma_f32_16x16x32_f16(ahh[i], bhh, accH[i][j], 0, 0, 0);
                accH[i][j] = __builtin_amdgcn_mfma_f32_16x16x32_f16(ahh[i], bhl, accH[i][j], 0, 0, 0);
                accH[i][j] = __builtin_amdgcn_mfma_f32_16x16x32_f16(ahl[i], bhh, accH[i][j], 0, 0, 0);
                accT[i][j] = __builtin_amdgcn_mfma_f32_16x16x32_f16(ahh[i], bth, accT[i][j], 0, 0, 0);
                accT[i][j] = __builtin_amdgcn_mfma_f32_16x16x32_f16(ahh[i], btl, accT[i][j], 0, 0, 0);
                accT[i][j] = __builtin_amdgcn_mfma_f32_16x16x32_f16(ahl[i], bth, accT[i][j], 0, 0, 0);
            }
        }
    }

    // epilogue: C/D layout col = lane&15, row = (lane>>4)*4 + reg (m89)
    float bhv[4], btv[4];
#pragma unroll
    for (int j = 0; j < 4; ++j) {
        bhv[j] = bh[n0 + wn + j * 16 + l15];
        btv[j] = bt[n0 + wn + j * 16 + l15];
    }
#pragma unroll
    for (int i = 0; i < 4; ++i) {
        const int rbase = m0 + wm + i * 16 + l4 * 4;
#pragma unroll
        for (int rg = 0; rg < 4; ++rg) {
            const int gr = rbase + rg;
            if (gr < M) {
                float* dh = &Hout[(size_t)gr * EMB + n0 + wn];
                float* dt = &Tout[(size_t)gr * EMB + n0 + wn];
#pragma unroll
                for (int j = 0; j < 4; ++j) {
                    const int col = j * 16 + l15;
                    dh[col] = accH[i][j][rg] + bhv[j];
                    dt[col] = accT[i][j][rg] + btv[j];
                }
            }
        }
    }
}

// Four edges per wave: 12 outstanding row-gathers for memory-level parallelism.
__global__ __launch_bounds__(256)
void edge_score4(const float* __restrict__ H, const float* __restrict__ T,
                 const float* __restrict__ rel, const int* __restrict__ ei,
                 const int* __restrict__ et, float* __restrict__ out, int E)
{
    const int lane = threadIdx.x & 63;
    const int wid = threadIdx.x >> 6;
    const int base = (blockIdx.x * 4 + wid) * 4;
    if (base >= E) return;

    int e[4];
#pragma unroll
    for (int u = 0; u < 4; ++u) {
        int eu = base + u;
        e[u] = eu < E ? eu : E - 1;      // clamp: dup work, identical writes
    }

    const int lo = lane * 4;
    float4 h[4], t[4], g[4];
#pragma unroll
    for (int u = 0; u < 4; ++u) h[u] = *(const float4*)&H[(size_t)ei[e[u]] * EMB + lo];
#pragma unroll
    for (int u = 0; u < 4; ++u) t[u] = *(const float4*)&T[(size_t)ei[E + e[u]] * EMB + lo];
#pragma unroll
    for (int u = 0; u < 4; ++u) g[u] = *(const float4*)&rel[(size_t)et[e[u]] * EMB + lo];

    float p[4];
#pragma unroll
    for (int u = 0; u < 4; ++u)
        p[u] = h[u].x * g[u].x * t[u].x + h[u].y * g[u].y * t[u].y
             + h[u].z * g[u].z * t[u].z + h[u].w * g[u].w * t[u].w;

#pragma unroll
    for (int off = 32; off > 0; off >>= 1) {
#pragma unroll
        for (int u = 0; u < 4; ++u) p[u] += __shfl_xor(p[u], off, 64);
    }
    if (lane == 0) {
#pragma unroll
        for (int u = 0; u < 4; ++u)
            out[e[u]] = 1.0f / (1.0f + expf(-p[u]));
    }
}

// Last-resort fallback: one block per edge, direct fp32 matvecs.
__global__ __launch_bounds__(256)
void edge_direct(const float* __restrict__ X, const int* __restrict__ ei,
                 const int* __restrict__ et,
                 const float* __restrict__ Wh, const float* __restrict__ bh,
                 const float* __restrict__ Wt, const float* __restrict__ bt,
                 const float* __restrict__ rel, float* __restrict__ out, int E)
{
    __shared__ float xsrc[EMB], xdst[EMB];
    __shared__ float red[256];
    const int e = blockIdx.x;
    const int tid = threadIdx.x;
    const int src = ei[e], dst = ei[E + e], r = et[e];

    xsrc[tid] = X[(size_t)src * EMB + tid];
    xdst[tid] = X[(size_t)dst * EMB + tid];
    __syncthreads();

    float ah = 0.f, at = 0.f;
    const float* wh = Wh + (size_t)tid * EMB;
    const float* wt = Wt + (size_t)tid * EMB;
#pragma unroll 8
    for (int k = 0; k < EMB; k += 4) {
        float4 w4 = *(const float4*)&wh[k];
        ah += w4.x * xsrc[k] + w4.y * xsrc[k + 1] + w4.z * xsrc[k + 2] + w4.w * xsrc[k + 3];
        float4 v4 = *(const float4*)&wt[k];
        at += v4.x * xdst[k] + v4.y * xdst[k + 1] + v4.z * xdst[k + 2] + v4.w * xdst[k + 3];
    }
    red[tid] = (ah + bh[tid]) * rel[(size_t)r * EMB + tid] * (at + bt[tid]);
    __syncthreads();
    for (int s2 = 128; s2 > 0; s2 >>= 1) {
        if (tid < s2) red[tid] += red[tid + s2];
        __syncthreads();
    }
    if (tid == 0) out[e] = 1.0f / (1.0f + expf(-red[0]));
}

extern "C" void kernel_launch(void* const* d_in, const int* in_sizes, int n_in,
                              void* d_out, int out_size, void* d_ws, size_t ws_size,
                              hipStream_t stream) {
    const float* x   = (const float*)d_in[0];
    const int*   ei  = (const int*)d_in[1];
    const int*   et  = (const int*)d_in[2];
    const float* Wh  = (const float*)d_in[3];
    const float* bh  = (const float*)d_in[4];
    const float* Wt  = (const float*)d_in[5];
    const float* bt  = (const float*)d_in[6];
    const float* rel = (const float*)d_in[7];
    float* out = (float*)d_out;

    const int M = in_sizes[0] / EMB;   // 100000 nodes
    const int E = in_sizes[2];         // 250000 edges

    const size_t szHT = (size_t)2 * M * EMB * sizeof(float);        // H + T
    const size_t szWs = (size_t)2 * 256 * 512 * sizeof(_Float16);   // Whs+Wts

    if (ws_size >= szHT + szWs) {
        float* H = (float*)d_ws;
        float* T = H + (size_t)M * EMB;
        _Float16* Whs = (_Float16*)((char*)d_ws + szHT);
        _Float16* Wts = Whs + (size_t)256 * 512;

        presplit_w<<<64, 256, 0, stream>>>(Wh, Wt, Whs, Wts);
        const int mtiles = (M + 127) / 128;
        const int nwg = 2 * mtiles;
        gemm_dual<<<nwg, 256, 0, stream>>>(x, Whs, Wts, bh, bt, H, T, M, nwg);
        edge_score4<<<(E + 15) / 16, 256, 0, stream>>>(H, T, rel, ei, et, out, E);
    } else {
        edge_direct<<<E, 256, 0, stream>>>(x, ei, et, Wh, bh, Wt, bt, rel, out, E);
    }
}

// Round 11
// 183.319 us; speedup vs baseline: 1.6591x; 1.1390x over previous
//
#include <hip/hip_runtime.h>
#include <math.h>

#define EMB 256

typedef _Float16 half8 __attribute__((ext_vector_type(8)));
typedef float f32x4 __attribute__((ext_vector_type(4)));

// ---------- async global->LDS, 16B per lane ----------
__device__ __forceinline__ void gload_lds16(const void* gsrc, void* lds) {
    __builtin_amdgcn_global_load_lds(
        (const __attribute__((address_space(1))) void*)gsrc,
        (__attribute__((address_space(3))) void*)lds,
        16, 0, 0);
}

// 8 f32 -> hi/lo fp16 split: x ~= hi + lo to ~2^-22 rel.
__device__ __forceinline__ void split8(const f32x4 a, const f32x4 b,
                                       half8& hi, half8& lo) {
#pragma unroll
    for (int i = 0; i < 4; ++i) {
        hi[i]     = (_Float16)a[i];
        lo[i]     = (_Float16)(a[i] - (float)hi[i]);
        hi[4 + i] = (_Float16)b[i];
        lo[4 + i] = (_Float16)(b[i] - (float)hi[4 + i]);
    }
}

// Pre-split W (Wh,Wt: 256x256 f32) into granule-swizzled f16 hi/lo:
// dst[r*512 + c*64 + g'*8 ..+8), g = part*4+seg, g' = g ^ (r&7).
__global__ void presplit_w(const float* __restrict__ Wh, const float* __restrict__ Wt,
                           _Float16* __restrict__ Whs, _Float16* __restrict__ Wts)
{
    const int g = blockIdx.x * 256 + threadIdx.x;
    const int m = g >> 5;                  // 0..511
    const int cs = g & 31;
    const int c = cs >> 2, seg = cs & 3;
    const float* src = (m < 256) ? Wh : Wt;
    _Float16* dst    = (m < 256) ? Whs : Wts;
    const int r = m & 255;

    const float* s = src + (size_t)r * EMB + c * 32 + seg * 8;
    const f32x4 v0 = *(const f32x4*)s;
    const f32x4 v1 = *(const f32x4*)(s + 4);
    half8 hi, lo;
    split8(v0, v1, hi, lo);
    _Float16* d = dst + (size_t)r * 512 + c * 64;
    const int sw = r & 7;
    *(half8*)(d + ((seg       ^ sw) << 3)) = hi;
    *(half8*)(d + (((4 + seg) ^ sw) << 3)) = lo;
}

// Dual-output GEMM, R7 structure + T4 counted-vmcnt pipeline:
// B (pre-split f16) is DOUBLE-buffered and staged by global_load_lds issued
// one full chunk ahead; the inter-phase barrier is raw s_barrier preceded by
// s_waitcnt vmcnt(8) lgkmcnt(0) -- the 8 newest B-gloads stay in flight
// across the barrier (never vmcnt(0) in the loop). A is single-buffered
// (global->reg->split->ds_write); its reg-prefetch drains via the compiler's
// own counted wait one full phase after issue.
// LDS: A 16KB + B 2x32KB = 80KB -> 2 blocks/CU.
__global__ __launch_bounds__(256, 2)
void gemm_dual(const float* __restrict__ X,
               const _Float16* __restrict__ Whs, const _Float16* __restrict__ Wts,
               const float* __restrict__ bh, const float* __restrict__ bt,
               float* __restrict__ Hout, float* __restrict__ Tout,
               int M, int nwg)
{
    __shared__ __align__(16) _Float16 Ax[128 * 64];        // 16 KB
    __shared__ __align__(16) _Float16 Bd[2][2][128 * 64];  // [buf][mat] 64 KB

    // bijective XCD swizzle (m204)
    const int fl = blockIdx.x;
    const int q = nwg >> 3, r = nwg & 7;
    const int xcd = fl & 7, ix = fl >> 3;
    const int wg = (xcd < r) ? xcd * (q + 1) + ix
                             : r * (q + 1) + (xcd - r) * q + ix;
    const int n0 = (wg & 1) << 7;
    const int m0 = (wg >> 1) << 7;

    const int tid = threadIdx.x;
    const int lane = tid & 63;
    const int wv = tid >> 6;
    const int wm = (wv >> 1) << 6;
    const int wn = (wv & 1) << 6;
    const int l15 = lane & 15, l4 = lane >> 4;

    // ---- A staging mapping: thread -> (row = tid>>1, 16-float half = tid&1)
    const int ar = tid >> 1;
    const int ahalf = tid & 1;
    const int gmA = m0 + ar;
    const float* aSrc = X + (size_t)(gmA < M ? gmA : M - 1) * EMB + ahalf * 16;
    char* aDst = (char*)Ax + ar * 128;
    const int ar7 = ar & 7;
    const int s0 = ahalf * 2, s1 = s0 + 1;
    const int oh0 = ((s0       ^ ar7) << 4), ol0 = (((4 + s0) ^ ar7) << 4);
    const int oh1 = ((s1       ^ ar7) << 4), ol1 = (((4 + s1) ^ ar7) << 4);

    // ---- B staging mapping: issue i: row = (tid>>3)+32i, phys granule tid&7
    const int brow = tid >> 3, bg = tid & 7;
    const char* bhSrc = (const char*)Whs + (size_t)(n0 + brow) * 1024 + bg * 16;
    const char* btSrc = (const char*)Wts + (size_t)(n0 + brow) * 1024 + bg * 16;
    const int bOff = brow * 128 + bg * 16;

    f32x4 accH[4][4], accT[4][4];
#pragma unroll
    for (int i = 0; i < 4; ++i)
#pragma unroll
        for (int j = 0; j < 4; ++j) {
            accH[i][j] = (f32x4){0.f, 0.f, 0.f, 0.f};
            accT[i][j] = (f32x4){0.f, 0.f, 0.f, 0.f};
        }

    // stage B chunk c into buffer b (8 gload_lds per thread)
    auto STAGE_B = [&](int b, int c) {
        const int cb = c << 7;
#pragma unroll
        for (int i = 0; i < 4; ++i) {
            gload_lds16(bhSrc + (size_t)i * 32768 + cb,
                        (char*)&Bd[b][0][0] + bOff + i * 4096);
            gload_lds16(btSrc + (size_t)i * 32768 + cb,
                        (char*)&Bd[b][1][0] + bOff + i * 4096);
        }
    };

    // prologue: A(0) regs + B(0) in flight
    f32x4 xg[4];
#pragma unroll
    for (int p = 0; p < 4; ++p) xg[p] = *(const f32x4*)(aSrc + p * 4);
    STAGE_B(0, 0);

    for (int c = 0; c < 8; ++c) {
        // top barrier: all waves finished reading A(c-1) (lgkm waited by MFMA use)
        __builtin_amdgcn_sched_barrier(0);
        __builtin_amdgcn_s_barrier();
        __builtin_amdgcn_sched_barrier(0);

        if (c < 7) STAGE_B((c + 1) & 1, c + 1);   // vmcnt +8, lands next phase

        // A split + ds_write (auto-wait drains A regs; B(c+1) stays in flight)
        {
            half8 hi0, lo0, hi1, lo1;
            split8(xg[0], xg[1], hi0, lo0);
            split8(xg[2], xg[3], hi1, lo1);
            *(half8*)(aDst + oh0) = hi0;
            *(half8*)(aDst + ol0) = lo0;
            *(half8*)(aDst + oh1) = hi1;
            *(half8*)(aDst + ol1) = lo1;
        }

        // counted wait: keep the 8 newest (B(c+1)) in flight; everything older
        // (B(c), A regs) complete. lgkmcnt(0): A ds_writes visible.
        asm volatile("s_waitcnt vmcnt(8) lgkmcnt(0)" ::: "memory");
        __builtin_amdgcn_sched_barrier(0);
        __builtin_amdgcn_s_barrier();
        __builtin_amdgcn_sched_barrier(0);

        // prefetch next A chunk (drains at next iter's split8, full-phase cover)
        if (c < 7) {
            const float* an = aSrc + (c + 1) * 32;
#pragma unroll
            for (int p = 0; p < 4; ++p) xg[p] = *(const f32x4*)(an + p * 4);
        }

        const char* BhB = (const char*)&Bd[c & 1][0][0];
        const char* BtB = (const char*)&Bd[c & 1][1][0];

        half8 ahh[4], ahl[4];
#pragma unroll
        for (int fi = 0; fi < 4; ++fi) {
            const int row = wm + fi * 16 + l15;
            const char* rb = (const char*)Ax + row * 128;
            ahh[fi] = *(const half8*)(rb + (((l4    ) ^ (row & 7)) << 4));
            ahl[fi] = *(const half8*)(rb + (((l4 + 4) ^ (row & 7)) << 4));
        }
#pragma unroll
        for (int j = 0; j < 4; ++j) {
            const int n = wn + j * 16 + l15;
            const int n7 = n & 7;
            const char* hr = BhB + n * 128;
            const char* tr = BtB + n * 128;
            const half8 bhh = *(const half8*)(hr + (((l4    ) ^ n7) << 4));
            const half8 bhl = *(const half8*)(hr + (((l4 + 4) ^ n7) << 4));
            const half8 bth = *(const half8*)(tr + (((l4    ) ^ n7) << 4));
            const half8 btl = *(const half8*)(tr + (((l4 + 4) ^ n7) << 4));
#pragma unroll
            for (int i = 0; i < 4; ++i) {
                accH[i][j] = __builtin_amdgcn_mfma_f32_16x16x32_f16(ahh[i], bhh, accH[i][j], 0, 0, 0);
                accH[i][j] = __builtin_amdgcn_mfma_f32_16x16x32_f16(ahh[i], bhl, accH[i][j], 0, 0, 0);
                accH[i][j] = __builtin_amdgcn_mfma_f32_16x16x32_f16(ahl[i], bhh, accH[i][j], 0, 0, 0);
                accT[i][j] = __builtin_amdgcn_mfma_f32_16x16x32_f16(ahh[i], bth, accT[i][j], 0, 0, 0);
                accT[i][j] = __builtin_amdgcn_mfma_f32_16x16x32_f16(ahh[i], btl, accT[i][j], 0, 0, 0);
                accT[i][j] = __builtin_amdgcn_mfma_f32_16x16x32_f16(ahl[i], bth, accT[i][j], 0, 0, 0);
            }
        }
    }

    // epilogue: C/D layout col = lane&15, row = (lane>>4)*4 + reg (m89)
    float bhv[4], btv[4];
#pragma unroll
    for (int j = 0; j < 4; ++j) {
        bhv[j] = bh[n0 + wn + j * 16 + l15];
        btv[j] = bt[n0 + wn + j * 16 + l15];
    }
#pragma unroll
    for (int i = 0; i < 4; ++i) {
        const int rbase = m0 + wm + i * 16 + l4 * 4;
#pragma unroll
        for (int rg = 0; rg < 4; ++rg) {
            const int gr = rbase + rg;
            if (gr < M) {
                float* dh = &Hout[(size_t)gr * EMB + n0 + wn];
                float* dt = &Tout[(size_t)gr * EMB + n0 + wn];
#pragma unroll
                for (int j = 0; j < 4; ++j) {
                    const int col = j * 16 + l15;
                    dh[col] = accH[i][j][rg] + bhv[j];
                    dt[col] = accT[i][j][rg] + btv[j];
                }
            }
        }
    }
}

// Four edges per wave: 12 outstanding row-gathers for memory-level parallelism.
__global__ __launch_bounds__(256)
void edge_score4(const float* __restrict__ H, const float* __restrict__ T,
                 const float* __restrict__ rel, const int* __restrict__ ei,
                 const int* __restrict__ et, float* __restrict__ out, int E)
{
    const int lane = threadIdx.x & 63;
    const int wid = threadIdx.x >> 6;
    const int base = (blockIdx.x * 4 + wid) * 4;
    if (base >= E) return;

    int e[4];
#pragma unroll
    for (int u = 0; u < 4; ++u) {
        int eu = base + u;
        e[u] = eu < E ? eu : E - 1;      // clamp: dup work, identical writes
    }

    const int lo = lane * 4;
    float4 h[4], t[4], g[4];
#pragma unroll
    for (int u = 0; u < 4; ++u) h[u] = *(const float4*)&H[(size_t)ei[e[u]] * EMB + lo];
#pragma unroll
    for (int u = 0; u < 4; ++u) t[u] = *(const float4*)&T[(size_t)ei[E + e[u]] * EMB + lo];
#pragma unroll
    for (int u = 0; u < 4; ++u) g[u] = *(const float4*)&rel[(size_t)et[e[u]] * EMB + lo];

    float p[4];
#pragma unroll
    for (int u = 0; u < 4; ++u)
        p[u] = h[u].x * g[u].x * t[u].x + h[u].y * g[u].y * t[u].y
             + h[u].z * g[u].z * t[u].z + h[u].w * g[u].w * t[u].w;

#pragma unroll
    for (int off = 32; off > 0; off >>= 1) {
#pragma unroll
        for (int u = 0; u < 4; ++u) p[u] += __shfl_xor(p[u], off, 64);
    }
    if (lane == 0) {
#pragma unroll
        for (int u = 0; u < 4; ++u)
            out[e[u]] = 1.0f / (1.0f + expf(-p[u]));
    }
}

// Last-resort fallback: one block per edge, direct fp32 matvecs.
__global__ __launch_bounds__(256)
void edge_direct(const float* __restrict__ X, const int* __restrict__ ei,
                 const int* __restrict__ et,
                 const float* __restrict__ Wh, const float* __restrict__ bh,
                 const float* __restrict__ Wt, const float* __restrict__ bt,
                 const float* __restrict__ rel, float* __restrict__ out, int E)
{
    __shared__ float xsrc[EMB], xdst[EMB];
    __shared__ float red[256];
    const int e = blockIdx.x;
    const int tid = threadIdx.x;
    const int src = ei[e], dst = ei[E + e], r = et[e];

    xsrc[tid] = X[(size_t)src * EMB + tid];
    xdst[tid] = X[(size_t)dst * EMB + tid];
    __syncthreads();

    float ah = 0.f, at = 0.f;
    const float* wh = Wh + (size_t)tid * EMB;
    const float* wt = Wt + (size_t)tid * EMB;
#pragma unroll 8
    for (int k = 0; k < EMB; k += 4) {
        float4 w4 = *(const float4*)&wh[k];
        ah += w4.x * xsrc[k] + w4.y * xsrc[k + 1] + w4.z * xsrc[k + 2] + w4.w * xsrc[k + 3];
        float4 v4 = *(const float4*)&wt[k];
        at += v4.x * xdst[k] + v4.y * xdst[k + 1] + v4.z * xdst[k + 2] + v4.w * xdst[k + 3];
    }
    red[tid] = (ah + bh[tid]) * rel[(size_t)r * EMB + tid] * (at + bt[tid]);
    __syncthreads();
    for (int s2 = 128; s2 > 0; s2 >>= 1) {
        if (tid < s2) red[tid] += red[tid + s2];
        __syncthreads();
    }
    if (tid == 0) out[e] = 1.0f / (1.0f + expf(-red[0]));
}

extern "C" void kernel_launch(void* const* d_in, const int* in_sizes, int n_in,
                              void* d_out, int out_size, void* d_ws, size_t ws_size,
                              hipStream_t stream) {
    const float* x   = (const float*)d_in[0];
    const int*   ei  = (const int*)d_in[1];
    const int*   et  = (const int*)d_in[2];
    const float* Wh  = (const float*)d_in[3];
    const float* bh  = (const float*)d_in[4];
    const float* Wt  = (const float*)d_in[5];
    const float* bt  = (const float*)d_in[6];
    const float* rel = (const float*)d_in[7];
    float* out = (float*)d_out;

    const int M = in_sizes[0] / EMB;   // 100000 nodes
    const int E = in_sizes[2];         // 250000 edges

    const size_t szHT = (size_t)2 * M * EMB * sizeof(float);        // H + T
    const size_t szWs = (size_t)2 * 256 * 512 * sizeof(_Float16);   // Whs+Wts

    if (ws_size >= szHT + szWs) {
        float* H = (float*)d_ws;
        float* T = H + (size_t)M * EMB;
        _Float16* Whs = (_Float16*)((char*)d_ws + szHT);
        _Float16* Wts = Whs + (size_t)256 * 512;

        presplit_w<<<64, 256, 0, stream>>>(Wh, Wt, Whs, Wts);
        const int mtiles = (M + 127) / 128;
        const int nwg = 2 * mtiles;
        gemm_dual<<<nwg, 256, 0, stream>>>(x, Whs, Wts, bh, bt, H, T, M, nwg);
        edge_score4<<<(E + 15) / 16, 256, 0, stream>>>(H, T, rel, ei, et, out, E);
    } else {
        edge_direct<<<E, 256, 0, stream>>>(x, ei, et, Wh, bh, Wt, bt, rel, out, E);
    }
}

// Round 12
// 177.414 us; speedup vs baseline: 1.7143x; 1.0333x over previous
//
#include <hip/hip_runtime.h>
#include <math.h>

#define EMB 256

typedef _Float16 half8 __attribute__((ext_vector_type(8)));
typedef float f32x4 __attribute__((ext_vector_type(4)));

// ---------- async global->LDS, 16B per lane ----------
__device__ __forceinline__ void gload_lds16(const void* gsrc, void* lds) {
    __builtin_amdgcn_global_load_lds(
        (const __attribute__((address_space(1))) void*)gsrc,
        (__attribute__((address_space(3))) void*)lds,
        16, 0, 0);
}

// 8 f32 -> hi/lo fp16 split: x ~= hi + lo to ~2^-22 rel.
__device__ __forceinline__ void split8(const f32x4 a, const f32x4 b,
                                       half8& hi, half8& lo) {
#pragma unroll
    for (int i = 0; i < 4; ++i) {
        hi[i]     = (_Float16)a[i];
        lo[i]     = (_Float16)(a[i] - (float)hi[i]);
        hi[4 + i] = (_Float16)b[i];
        lo[4 + i] = (_Float16)(b[i] - (float)hi[4 + i]);
    }
}

// Pre-split W (Wh,Wt: 256x256 f32) into granule-swizzled f16 hi/lo:
// dst[r*512 + c*64 + g'*8 ..+8), g = part*4+seg, g' = g ^ (r&7).
__global__ void presplit_w(const float* __restrict__ Wh, const float* __restrict__ Wt,
                           _Float16* __restrict__ Whs, _Float16* __restrict__ Wts)
{
    const int g = blockIdx.x * 256 + threadIdx.x;
    const int m = g >> 5;                  // 0..511
    const int cs = g & 31;
    const int c = cs >> 2, seg = cs & 3;
    const float* src = (m < 256) ? Wh : Wt;
    _Float16* dst    = (m < 256) ? Whs : Wts;
    const int r = m & 255;

    const float* s = src + (size_t)r * EMB + c * 32 + seg * 8;
    const f32x4 v0 = *(const f32x4*)s;
    const f32x4 v1 = *(const f32x4*)(s + 4);
    half8 hi, lo;
    split8(v0, v1, hi, lo);
    _Float16* d = dst + (size_t)r * 512 + c * 64;
    const int sw = r & 7;
    *(half8*)(d + ((seg       ^ sw) << 3)) = hi;
    *(half8*)(d + (((4 + seg) ^ sw) << 3)) = lo;
}

// Dual-output GEMM, 8-phase-style fine interleave (guide §5.5 T3+T4+T5):
// per chunk: {stage B(c+1) + A-split + counted vmcnt + barrier}, then 4 phases
// (one per j-quadrant): {ds_read B-frags (A-frags in phase 0) -> s_barrier ->
// lgkmcnt(0) -> setprio(1) 24xMFMA setprio(0) -> s_barrier}. Counted vmcnt(8)
// keeps next-chunk B-gloads in flight across barriers (vmcnt(0) only at c=7).
// LDS: A 16KB + B 2x32KB = 80KB -> 2 blocks/CU.
__global__ __launch_bounds__(256, 2)
void gemm_dual(const float* __restrict__ X,
               const _Float16* __restrict__ Whs, const _Float16* __restrict__ Wts,
               const float* __restrict__ bh, const float* __restrict__ bt,
               float* __restrict__ Hout, float* __restrict__ Tout,
               int M, int nwg)
{
    __shared__ __align__(16) _Float16 Ax[128 * 64];        // 16 KB
    __shared__ __align__(16) _Float16 Bd[2][2][128 * 64];  // [buf][mat] 64 KB

    // bijective XCD swizzle (m204)
    const int fl = blockIdx.x;
    const int q = nwg >> 3, r = nwg & 7;
    const int xcd = fl & 7, ix = fl >> 3;
    const int wg = (xcd < r) ? xcd * (q + 1) + ix
                             : r * (q + 1) + (xcd - r) * q + ix;
    const int n0 = (wg & 1) << 7;
    const int m0 = (wg >> 1) << 7;

    const int tid = threadIdx.x;
    const int lane = tid & 63;
    const int wv = tid >> 6;
    const int wm = (wv >> 1) << 6;
    const int wn = (wv & 1) << 6;
    const int l15 = lane & 15, l4 = lane >> 4;

    // ---- A staging mapping: thread -> (row = tid>>1, 16-float half = tid&1)
    const int ar = tid >> 1;
    const int ahalf = tid & 1;
    const int gmA = m0 + ar;
    const float* aSrc = X + (size_t)(gmA < M ? gmA : M - 1) * EMB + ahalf * 16;
    char* aDst = (char*)Ax + ar * 128;
    const int ar7 = ar & 7;
    const int s0 = ahalf * 2, s1 = s0 + 1;
    const int oh0 = ((s0       ^ ar7) << 4), ol0 = (((4 + s0) ^ ar7) << 4);
    const int oh1 = ((s1       ^ ar7) << 4), ol1 = (((4 + s1) ^ ar7) << 4);

    // ---- B staging mapping: issue i: row = (tid>>3)+32i, phys granule tid&7
    const int brow = tid >> 3, bg = tid & 7;
    const char* bhSrc = (const char*)Whs + (size_t)(n0 + brow) * 1024 + bg * 16;
    const char* btSrc = (const char*)Wts + (size_t)(n0 + brow) * 1024 + bg * 16;
    const int bOff = brow * 128 + bg * 16;

    f32x4 accH[4][4], accT[4][4];
#pragma unroll
    for (int i = 0; i < 4; ++i)
#pragma unroll
        for (int j = 0; j < 4; ++j) {
            accH[i][j] = (f32x4){0.f, 0.f, 0.f, 0.f};
            accT[i][j] = (f32x4){0.f, 0.f, 0.f, 0.f};
        }

    // stage B chunk c into buffer b (8 gload_lds per thread)
    auto STAGE_B = [&](int b, int c) {
        const int cb = c << 7;
#pragma unroll
        for (int i = 0; i < 4; ++i) {
            gload_lds16(bhSrc + (size_t)i * 32768 + cb,
                        (char*)&Bd[b][0][0] + bOff + i * 4096);
            gload_lds16(btSrc + (size_t)i * 32768 + cb,
                        (char*)&Bd[b][1][0] + bOff + i * 4096);
        }
    };

    // prologue: A(0) regs + B(0) in flight
    f32x4 xg[4];
#pragma unroll
    for (int p = 0; p < 4; ++p) xg[p] = *(const f32x4*)(aSrc + p * 4);
    STAGE_B(0, 0);

    for (int c = 0; c < 8; ++c) {
        // top barrier: Ax(c-1)/Bd[(c+1)&1] reads of earlier chunks complete
        if (c) {
            __builtin_amdgcn_sched_barrier(0);
            __builtin_amdgcn_s_barrier();
            __builtin_amdgcn_sched_barrier(0);
        }

        if (c < 7) STAGE_B((c + 1) & 1, c + 1);   // vmcnt +8, lands next chunk

        // A split + ds_write (compiler drains A regs with its own counted wait)
        {
            half8 hi0, lo0, hi1, lo1;
            split8(xg[0], xg[1], hi0, lo0);
            split8(xg[2], xg[3], hi1, lo1);
            *(half8*)(aDst + oh0) = hi0;
            *(half8*)(aDst + ol0) = lo0;
            *(half8*)(aDst + oh1) = hi1;
            *(half8*)(aDst + ol1) = lo1;
        }

        // counted wait: B(c) landed, A ds_writes visible; B(c+1) stays in flight.
        if (c < 7) asm volatile("s_waitcnt vmcnt(8) lgkmcnt(0)" ::: "memory");
        else       asm volatile("s_waitcnt vmcnt(0) lgkmcnt(0)" ::: "memory");
        __builtin_amdgcn_sched_barrier(0);
        __builtin_amdgcn_s_barrier();
        __builtin_amdgcn_sched_barrier(0);

        // prefetch next A chunk (drains at next iter's split8, full-phase cover)
        if (c < 7) {
            const float* an = aSrc + (c + 1) * 32;
#pragma unroll
            for (int p = 0; p < 4; ++p) xg[p] = *(const f32x4*)(an + p * 4);
        }

        const char* BhB = (const char*)&Bd[c & 1][0][0];
        const char* BtB = (const char*)&Bd[c & 1][1][0];

        half8 ahh[4], ahl[4];
        // ---- 4 fine phases, one per j-quadrant ----
#pragma unroll
        for (int j = 0; j < 4; ++j) {
            if (j == 0) {
                // A frag reads (phase 0 only; regs live across phases)
#pragma unroll
                for (int fi = 0; fi < 4; ++fi) {
                    const int row = wm + fi * 16 + l15;
                    const char* rb = (const char*)Ax + row * 128;
                    ahh[fi] = *(const half8*)(rb + (((l4    ) ^ (row & 7)) << 4));
                    ahl[fi] = *(const half8*)(rb + (((l4 + 4) ^ (row & 7)) << 4));
                }
            }
            const int n = wn + j * 16 + l15;
            const int n7 = n & 7;
            const char* hr = BhB + n * 128;
            const char* tr = BtB + n * 128;
            const half8 bhh = *(const half8*)(hr + (((l4    ) ^ n7) << 4));
            const half8 bhl = *(const half8*)(hr + (((l4 + 4) ^ n7) << 4));
            const half8 bth = *(const half8*)(tr + (((l4    ) ^ n7) << 4));
            const half8 btl = *(const half8*)(tr + (((l4 + 4) ^ n7) << 4));

            // phase fence: all waves' reads queued before anyone computes
            __builtin_amdgcn_sched_barrier(0);
            __builtin_amdgcn_s_barrier();
            asm volatile("s_waitcnt lgkmcnt(0)" ::: "memory");
            __builtin_amdgcn_sched_barrier(0);

            __builtin_amdgcn_s_setprio(1);
#pragma unroll
            for (int i = 0; i < 4; ++i) {
                accH[i][j] = __builtin_amdgcn_mfma_f32_16x16x32_f16(ahh[i], bhh, accH[i][j], 0, 0, 0);
                accH[i][j] = __builtin_amdgcn_mfma_f32_16x16x32_f16(ahh[i], bhl, accH[i][j], 0, 0, 0);
                accH[i][j] = __builtin_amdgcn_mfma_f32_16x16x32_f16(ahl[i], bhh, accH[i][j], 0, 0, 0);
                accT[i][j] = __builtin_amdgcn_mfma_f32_16x16x32_f16(ahh[i], bth, accT[i][j], 0, 0, 0);
                accT[i][j] = __builtin_amdgcn_mfma_f32_16x16x32_f16(ahh[i], btl, accT[i][j], 0, 0, 0);
                accT[i][j] = __builtin_amdgcn_mfma_f32_16x16x32_f16(ahl[i], bth, accT[i][j], 0, 0, 0);
            }
            __builtin_amdgcn_s_setprio(0);

            if (j < 3) {
                __builtin_amdgcn_sched_barrier(0);
                __builtin_amdgcn_s_barrier();
                __builtin_amdgcn_sched_barrier(0);
            }
        }
    }

    // epilogue: C/D layout col = lane&15, row = (lane>>4)*4 + reg (m89)
    float bhv[4], btv[4];
#pragma unroll
    for (int j = 0; j < 4; ++j) {
        bhv[j] = bh[n0 + wn + j * 16 + l15];
        btv[j] = bt[n0 + wn + j * 16 + l15];
    }
#pragma unroll
    for (int i = 0; i < 4; ++i) {
        const int rbase = m0 + wm + i * 16 + l4 * 4;
#pragma unroll
        for (int rg = 0; rg < 4; ++rg) {
            const int gr = rbase + rg;
            if (gr < M) {
                float* dh = &Hout[(size_t)gr * EMB + n0 + wn];
                float* dt = &Tout[(size_t)gr * EMB + n0 + wn];
#pragma unroll
                for (int j = 0; j < 4; ++j) {
                    const int col = j * 16 + l15;
                    dh[col] = accH[i][j][rg] + bhv[j];
                    dt[col] = accT[i][j][rg] + btv[j];
                }
            }
        }
    }
}

// Four edges per wave: 12 outstanding row-gathers for memory-level parallelism.
__global__ __launch_bounds__(256)
void edge_score4(const float* __restrict__ H, const float* __restrict__ T,
                 const float* __restrict__ rel, const int* __restrict__ ei,
                 const int* __restrict__ et, float* __restrict__ out, int E)
{
    const int lane = threadIdx.x & 63;
    const int wid = threadIdx.x >> 6;
    const int base = (blockIdx.x * 4 + wid) * 4;
    if (base >= E) return;

    int e[4];
#pragma unroll
    for (int u = 0; u < 4; ++u) {
        int eu = base + u;
        e[u] = eu < E ? eu : E - 1;      // clamp: dup work, identical writes
    }

    const int lo = lane * 4;
    float4 h[4], t[4], g[4];
#pragma unroll
    for (int u = 0; u < 4; ++u) h[u] = *(const float4*)&H[(size_t)ei[e[u]] * EMB + lo];
#pragma unroll
    for (int u = 0; u < 4; ++u) t[u] = *(const float4*)&T[(size_t)ei[E + e[u]] * EMB + lo];
#pragma unroll
    for (int u = 0; u < 4; ++u) g[u] = *(const float4*)&rel[(size_t)et[e[u]] * EMB + lo];

    float p[4];
#pragma unroll
    for (int u = 0; u < 4; ++u)
        p[u] = h[u].x * g[u].x * t[u].x + h[u].y * g[u].y * t[u].y
             + h[u].z * g[u].z * t[u].z + h[u].w * g[u].w * t[u].w;

#pragma unroll
    for (int off = 32; off > 0; off >>= 1) {
#pragma unroll
        for (int u = 0; u < 4; ++u) p[u] += __shfl_xor(p[u], off, 64);
    }
    if (lane == 0) {
#pragma unroll
        for (int u = 0; u < 4; ++u)
            out[e[u]] = 1.0f / (1.0f + expf(-p[u]));
    }
}

// Last-resort fallback: one block per edge, direct fp32 matvecs.
__global__ __launch_bounds__(256)
void edge_direct(const float* __restrict__ X, const int* __restrict__ ei,
                 const int* __restrict__ et,
                 const float* __restrict__ Wh, const float* __restrict__ bh,
                 const float* __restrict__ Wt, const float* __restrict__ bt,
                 const float* __restrict__ rel, float* __restrict__ out, int E)
{
    __shared__ float xsrc[EMB], xdst[EMB];
    __shared__ float red[256];
    const int e = blockIdx.x;
    const int tid = threadIdx.x;
    const int src = ei[e], dst = ei[E + e], r = et[e];

    xsrc[tid] = X[(size_t)src * EMB + tid];
    xdst[tid] = X[(size_t)dst * EMB + tid];
    __syncthreads();

    float ah = 0.f, at = 0.f;
    const float* wh = Wh + (size_t)tid * EMB;
    const float* wt = Wt + (size_t)tid * EMB;
#pragma unroll 8
    for (int k = 0; k < EMB; k += 4) {
        float4 w4 = *(const float4*)&wh[k];
        ah += w4.x * xsrc[k] + w4.y * xsrc[k + 1] + w4.z * xsrc[k + 2] + w4.w * xsrc[k + 3];
        float4 v4 = *(const float4*)&wt[k];
        at += v4.x * xdst[k] + v4.y * xdst[k + 1] + v4.z * xdst[k + 2] + v4.w * xdst[k + 3];
    }
    red[tid] = (ah + bh[tid]) * rel[(size_t)r * EMB + tid] * (at + bt[tid]);
    __syncthreads();
    for (int s2 = 128; s2 > 0; s2 >>= 1) {
        if (tid < s2) red[tid] += red[tid + s2];
        __syncthreads();
    }
    if (tid == 0) out[e] = 1.0f / (1.0f + expf(-red[0]));
}

extern "C" void kernel_launch(void* const* d_in, const int* in_sizes, int n_in,
                              void* d_out, int out_size, void* d_ws, size_t ws_size,
                              hipStream_t stream) {
    const float* x   = (const float*)d_in[0];
    const int*   ei  = (const int*)d_in[1];
    const int*   et  = (const int*)d_in[2];
    const float* Wh  = (const float*)d_in[3];
    const float* bh  = (const float*)d_in[4];
    const float* Wt  = (const float*)d_in[5];
    const float* bt  = (const float*)d_in[6];
    const float* rel = (const float*)d_in[7];
    float* out = (float*)d_out;

    const int M = in_sizes[0] / EMB;   // 100000 nodes
    const int E = in_sizes[2];         // 250000 edges

    const size_t szHT = (size_t)2 * M * EMB * sizeof(float);        // H + T
    const size_t szWs = (size_t)2 * 256 * 512 * sizeof(_Float16);   // Whs+Wts

    if (ws_size >= szHT + szWs) {
        float* H = (float*)d_ws;
        float* T = H + (size_t)M * EMB;
        _Float16* Whs = (_Float16*)((char*)d_ws + szHT);
        _Float16* Wts = Whs + (size_t)256 * 512;

        presplit_w<<<64, 256, 0, stream>>>(Wh, Wt, Whs, Wts);
        const int mtiles = (M + 127) / 128;
        const int nwg = 2 * mtiles;
        gemm_dual<<<nwg, 256, 0, stream>>>(x, Whs, Wts, bh, bt, H, T, M, nwg);
        edge_score4<<<(E + 15) / 16, 256, 0, stream>>>(H, T, rel, ei, et, out, E);
    } else {
        edge_direct<<<E, 256, 0, stream>>>(x, ei, et, Wh, bh, Wt, bt, rel, out, E);
    }
}